// Round 1
// baseline (9442.113 us; speedup 1.0000x reference)
//
#include <hip/hip_runtime.h>
#include <math.h>

#define D_MODEL 1024
#define HEADS 16
#define HEAD_DIM 64
#define SEQ 2048
#define BATCH 2

// ---------------------------------------------------------------------------
// Tiled f32 GEMM: out[M,N] = X[M,K] @ W[K,N] + bias[N]
// HEAD_SPLIT: write out in [B,H,S,Dh] layout (for Q/K/V); else row-major [M,N].
// M=BATCH*SEQ=4096, N=K=D_MODEL=1024 — all divisible by 16, no bounds checks.
// ---------------------------------------------------------------------------
template <bool HEAD_SPLIT>
__global__ __launch_bounds__(256) void gemm_bias(
    const float* __restrict__ X, const float* __restrict__ W,
    const float* __restrict__ bias, float* __restrict__ out,
    int M, int N, int K) {
    __shared__ float As[16][17];
    __shared__ float Bs[16][17];
    const int tx = threadIdx.x, ty = threadIdx.y;
    const int row = blockIdx.y * 16 + ty;
    const int col = blockIdx.x * 16 + tx;
    float acc = 0.f;
    for (int k0 = 0; k0 < K; k0 += 16) {
        As[ty][tx] = X[(size_t)row * K + k0 + tx];
        Bs[ty][tx] = W[(size_t)(k0 + ty) * N + col];
        __syncthreads();
#pragma unroll
        for (int kk = 0; kk < 16; ++kk) acc += As[ty][kk] * Bs[kk][tx];
        __syncthreads();
    }
    acc += bias[col];
    if (HEAD_SPLIT) {
        const int b = row / SEQ, s = row % SEQ;
        const int h = col / HEAD_DIM, dh = col % HEAD_DIM;
        out[(((size_t)(b * HEADS + h)) * SEQ + s) * HEAD_DIM + dh] = acc;
    } else {
        out[(size_t)row * N + col] = acc;
    }
}

// ---------------------------------------------------------------------------
// Attention: one block (256 threads) per (b, h, q) query row.
//  - scores[k] = dot(q, K[k]) * 1/8, masked -> -inf
//  - block softmax with fully-masked-row -> 0 semantics
//  - PV: 4-way k-split, coalesced V reads, LDS partial reduce
// Writes merged [B,S,D] layout directly for the output projection.
// ---------------------------------------------------------------------------
__global__ __launch_bounds__(256) void attn_kernel(
    const float* __restrict__ Q, const float* __restrict__ Km,
    const float* __restrict__ Vm, const int* __restrict__ mask,
    float* __restrict__ Y) {
    __shared__ float sc[SEQ];       // 8 KB scores/weights
    __shared__ float qs[HEAD_DIM];
    __shared__ float red[256];
    __shared__ float py[4][HEAD_DIM];

    const int idx = blockIdx.x;
    const int q = idx % SEQ;
    const int h = (idx / SEQ) % HEADS;
    const int b = idx / (SEQ * HEADS);
    const int tid = threadIdx.x;

    const size_t bh = (size_t)(b * HEADS + h);
    const float* Qp = Q + (bh * SEQ + q) * HEAD_DIM;
    if (tid < HEAD_DIM) qs[tid] = Qp[tid];
    __syncthreads();

    const float* Kb = Km + bh * SEQ * HEAD_DIM;
    const int* mb = mask + b * SEQ;

    float pmax = -INFINITY;
    for (int k = tid; k < SEQ; k += 256) {
        const float* Kr = Kb + (size_t)k * HEAD_DIM;
        float s = 0.f;
#pragma unroll
        for (int d = 0; d < HEAD_DIM; ++d) s += qs[d] * Kr[d];
        s = mb[k] ? s * 0.125f : -INFINITY;
        sc[k] = s;
        pmax = fmaxf(pmax, s);
    }
    red[tid] = pmax;
    __syncthreads();
    for (int off = 128; off > 0; off >>= 1) {
        if (tid < off) red[tid] = fmaxf(red[tid], red[tid + off]);
        __syncthreads();
    }
    const float m = red[0];
    __syncthreads();  // before reusing red[]

    float psum = 0.f;
    for (int k = tid; k < SEQ; k += 256) {
        const float p = (m == -INFINITY) ? 0.f : __expf(sc[k] - m);
        sc[k] = p;
        psum += p;
    }
    red[tid] = psum;
    __syncthreads();
    for (int off = 128; off > 0; off >>= 1) {
        if (tid < off) red[tid] += red[tid + off];
        __syncthreads();
    }
    const float sum = red[0];
    const float inv = (sum > 0.f) ? 1.f / sum : 0.f;

    // PV: thread t handles dh = t&63, key-slice t>>6 (stride 4)
    const int dh = tid & 63;
    const int grp = tid >> 6;
    const float* Vb = Vm + bh * SEQ * HEAD_DIM;
    float acc = 0.f;
    for (int k = grp; k < SEQ; k += 4) {
        acc += sc[k] * Vb[(size_t)k * HEAD_DIM + dh];
    }
    py[grp][dh] = acc;
    __syncthreads();
    if (tid < HEAD_DIM) {
        const float y = (py[0][tid] + py[1][tid] + py[2][tid] + py[3][tid]) * inv;
        Y[((size_t)(b * SEQ + q)) * D_MODEL + h * HEAD_DIM + tid] = y;
    }
}

// ---------------------------------------------------------------------------
extern "C" void kernel_launch(void* const* d_in, const int* in_sizes, int n_in,
                              void* d_out, int out_size, void* d_ws, size_t ws_size,
                              hipStream_t stream) {
    const float* x   = (const float*)d_in[0];
    const int*   mask= (const int*)  d_in[1];
    const float* Wq  = (const float*)d_in[2];
    const float* bq  = (const float*)d_in[3];
    const float* Wk  = (const float*)d_in[4];
    const float* bk  = (const float*)d_in[5];
    const float* Wv  = (const float*)d_in[6];
    const float* bv  = (const float*)d_in[7];
    const float* Wp  = (const float*)d_in[8];
    const float* bp  = (const float*)d_in[9];
    float* out = (float*)d_out;

    float* ws = (float*)d_ws;
    const size_t per = (size_t)BATCH * HEADS * SEQ * HEAD_DIM;  // 4M floats
    float* Q = ws;
    float* K = ws + per;
    float* V = ws + 2 * per;
    float* Y = ws + 3 * per;  // merged [B,S,D]

    const int M = BATCH * SEQ;
    dim3 blk(16, 16);
    dim3 grd(D_MODEL / 16, M / 16);

    gemm_bias<true><<<grd, blk, 0, stream>>>(x, Wq, bq, Q, M, D_MODEL, D_MODEL);
    gemm_bias<true><<<grd, blk, 0, stream>>>(x, Wk, bk, K, M, D_MODEL, D_MODEL);
    gemm_bias<true><<<grd, blk, 0, stream>>>(x, Wv, bv, V, M, D_MODEL, D_MODEL);

    attn_kernel<<<BATCH * HEADS * SEQ, 256, 0, stream>>>(Q, K, V, mask, Y);

    gemm_bias<false><<<grd, blk, 0, stream>>>(Y, Wp, bp, out, M, D_MODEL, D_MODEL);
}

// Round 2
// 2176.286 us; speedup vs baseline: 4.3386x; 4.3386x over previous
//
#include <hip/hip_runtime.h>
#include <math.h>

#define D_MODEL 1024
#define HEADS 16
#define HEAD_DIM 64
#define SEQ 2048
#define BATCH 2
#define KVT 64
#define QTILE 64

typedef __attribute__((ext_vector_type(8))) short bf16x8;
typedef __attribute__((ext_vector_type(4))) float f32x4;

__device__ __forceinline__ short f2bf(float f) {
    union { float f; unsigned u; } v; v.f = f;
    unsigned r = (v.u + 0x7FFFu + ((v.u >> 16) & 1u)) >> 16;
    return (short)r;
}

// ---------------------------------------------------------------------------
// Tiled f32 GEMM: out = X[M,K] @ W[K,N] + bias[N]
// MODE 0: f32 row-major [M,N]     (final projection)
// MODE 1: bf16 head-split [B,H,S,Dh]   (Q, K)
// MODE 2: bf16 transposed [B,H,Dh,S]   (V^T)
// ---------------------------------------------------------------------------
template <int MODE>
__global__ __launch_bounds__(256) void gemm_bias(
    const float* __restrict__ X, const float* __restrict__ W,
    const float* __restrict__ bias, float* __restrict__ outf,
    short* __restrict__ outb, int M, int N, int K) {
    __shared__ float As[16][17];
    __shared__ float Bs[16][17];
    const int tx = threadIdx.x, ty = threadIdx.y;
    const int row = blockIdx.y * 16 + ty;
    const int col = blockIdx.x * 16 + tx;
    float acc = 0.f;
    for (int k0 = 0; k0 < K; k0 += 16) {
        As[ty][tx] = X[(size_t)row * K + k0 + tx];
        Bs[ty][tx] = W[(size_t)(k0 + ty) * N + col];
        __syncthreads();
#pragma unroll
        for (int kk = 0; kk < 16; ++kk) acc += As[ty][kk] * Bs[kk][tx];
        __syncthreads();
    }
    acc += bias[col];
    if (MODE == 0) {
        outf[(size_t)row * N + col] = acc;
    } else {
        const int b = row / SEQ, s = row % SEQ;
        const int h = col / HEAD_DIM, dh = col % HEAD_DIM;
        if (MODE == 1)
            outb[(((size_t)(b * HEADS + h)) * SEQ + s) * HEAD_DIM + dh] = f2bf(acc);
        else
            outb[(((size_t)(b * HEADS + h)) * HEAD_DIM + dh) * SEQ + s] = f2bf(acc);
    }
}

// ---------------------------------------------------------------------------
// Flash attention, bf16 MFMA (16x16x32).
// Block = 256 threads = 4 waves; one block per (b,h, 64-query tile).
// Wave w owns 16 query rows. Loop over 32 KV tiles of 64 keys:
//   stage K [key][dh] and Vt [dh][key] in XOR-swizzled LDS, QK^T by MFMA,
//   online softmax (row = (lane>>4)*4+r across 16 lanes, shfl_xor reduce),
//   P -> per-wave swizzled LDS (bf16), PV by MFMA.
// Writes Y merged [B,S,D] f32.
// ---------------------------------------------------------------------------
__global__ __launch_bounds__(256) void flash_attn(
    const short* __restrict__ Q, const short* __restrict__ K,
    const short* __restrict__ Vt, const int* __restrict__ mask,
    float* __restrict__ Y) {
    __shared__ unsigned char kt[KVT * 128];        // K tile,  swizzled
    __shared__ unsigned char vt[HEAD_DIM * 128];   // Vt tile, swizzled
    __shared__ unsigned char pb[4][16 * 128];      // per-wave P, swizzled
    __shared__ float maskadd[KVT];

    const int tid = threadIdx.x;
    const int wave = tid >> 6;
    const int lane = tid & 63;
    const int l15 = lane & 15;
    const int lhi = lane >> 4;  // 0..3

    const int blk = blockIdx.x;
    const int qt = blk & 31;   // S/QTILE
    const int bh = blk >> 5;   // b*HEADS + h
    const int b = bh >> 4;
    const int h = bh & 15;

    const int q0 = qt * QTILE + wave * 16;

    // Q fragments: lane holds Q[q0 + (l&15)][8*lhi + i (+32*c)]
    const short* Qp = Q + ((size_t)bh * SEQ + q0 + l15) * HEAD_DIM;
    bf16x8 qf[2];
    qf[0] = *(const bf16x8*)(Qp + 8 * lhi);
    qf[1] = *(const bf16x8*)(Qp + 8 * lhi + 32);

    const unsigned char* Kb = (const unsigned char*)(K + (size_t)bh * SEQ * HEAD_DIM);
    const unsigned char* Vb = (const unsigned char*)(Vt + (size_t)bh * HEAD_DIM * SEQ);
    const int* mb = mask + b * SEQ;

    f32x4 accO[4];
    float mrow[4], lrow[4];
#pragma unroll
    for (int i = 0; i < 4; ++i) {
        accO[i] = (f32x4){0.f, 0.f, 0.f, 0.f};
        mrow[i] = -INFINITY;
        lrow[i] = 0.f;
    }

    for (int kv = 0; kv < SEQ / KVT; ++kv) {
        __syncthreads();
        // ---- stage K tile: 64 rows x 128B, swizzle byte ^= (key&7)<<4
#pragma unroll
        for (int p = 0; p < 2; ++p) {
            const int o = p * 256 + tid;          // 16B units, 512 total
            const int key = o >> 3;
            const int inner = (o & 7) * 16;
            uint4 d = *(const uint4*)(Kb + (size_t)kv * KVT * 128 + key * 128 + inner);
            *(uint4*)(kt + key * 128 + (inner ^ ((key & 7) << 4))) = d;
        }
        // ---- stage Vt tile: 64 dh-rows (global stride SEQ*2) x 128B
#pragma unroll
        for (int p = 0; p < 2; ++p) {
            const int o = p * 256 + tid;
            const int dh = o >> 3;
            const int inner = (o & 7) * 16;
            uint4 d = *(const uint4*)(Vb + (size_t)dh * (SEQ * 2) + kv * 128 + inner);
            *(uint4*)(vt + dh * 128 + (inner ^ ((dh & 7) << 4))) = d;
        }
        if (tid < KVT) maskadd[tid] = mb[kv * KVT + tid] ? 0.f : -INFINITY;
        __syncthreads();

        // ---- QK^T: accS[nt] covers keys nt*16 + (l&15), rows lhi*4+r
        f32x4 accS[4];
#pragma unroll
        for (int nt = 0; nt < 4; ++nt) accS[nt] = (f32x4){0.f, 0.f, 0.f, 0.f};
#pragma unroll
        for (int c = 0; c < 2; ++c) {
#pragma unroll
            for (int nt = 0; nt < 4; ++nt) {
                const int key = l15 + 16 * nt;
                bf16x8 kf = *(const bf16x8*)(kt + key * 128 +
                                             ((16 * lhi + 64 * c) ^ ((key & 7) << 4)));
                accS[nt] = __builtin_amdgcn_mfma_f32_16x16x32_bf16(qf[c], kf, accS[nt], 0, 0, 0);
            }
        }

        // ---- masked scores
        float sv[4][4];
#pragma unroll
        for (int nt = 0; nt < 4; ++nt) {
            const float ma = maskadd[l15 + 16 * nt];
#pragma unroll
            for (int r = 0; r < 4; ++r) sv[nt][r] = accS[nt][r] * 0.125f + ma;
        }

        // ---- online softmax per row r (row = lhi*4+r, spread over 16 lanes)
#pragma unroll
        for (int r = 0; r < 4; ++r) {
            float tmax = fmaxf(fmaxf(sv[0][r], sv[1][r]), fmaxf(sv[2][r], sv[3][r]));
#pragma unroll
            for (int m = 1; m < 16; m <<= 1) tmax = fmaxf(tmax, __shfl_xor(tmax, m, 16));
            const float mn = fmaxf(mrow[r], tmax);
            const float alpha = (mn == -INFINITY) ? 1.f : __expf(mrow[r] - mn);
            float p[4];
            float rs = 0.f;
#pragma unroll
            for (int nt = 0; nt < 4; ++nt) {
                p[nt] = (mn == -INFINITY) ? 0.f : __expf(sv[nt][r] - mn);
                rs += p[nt];
            }
#pragma unroll
            for (int m = 1; m < 16; m <<= 1) rs += __shfl_xor(rs, m, 16);
            lrow[r] = lrow[r] * alpha + rs;
            mrow[r] = mn;
#pragma unroll
            for (int d = 0; d < 4; ++d) accO[d][r] *= alpha;
            // write P row to per-wave LDS (bf16, swizzled)
            const int qrow = lhi * 4 + r;
            unsigned char* pw = pb[wave] + qrow * 128;
            const int sw = (qrow & 7) << 4;
#pragma unroll
            for (int nt = 0; nt < 4; ++nt)
                *(short*)(pw + (((l15 + 16 * nt) * 2) ^ sw)) = f2bf(p[nt]);
        }

        // ---- PV: O[dh-tile] += P[16q x 32k] @ V[32k x 16dh]
#pragma unroll
        for (int c = 0; c < 2; ++c) {
            bf16x8 pf = *(const bf16x8*)(pb[wave] + l15 * 128 +
                                         ((16 * lhi + 64 * c) ^ ((l15 & 7) << 4)));
#pragma unroll
            for (int d = 0; d < 4; ++d) {
                const int dh = l15 + 16 * d;
                bf16x8 vf = *(const bf16x8*)(vt + dh * 128 +
                                             ((16 * lhi + 64 * c) ^ ((dh & 7) << 4)));
                accO[d] = __builtin_amdgcn_mfma_f32_16x16x32_bf16(pf, vf, accO[d], 0, 0, 0);
            }
        }
    }

    // ---- epilogue: O / l, write merged [B,S,D]
    float inv[4];
#pragma unroll
    for (int r = 0; r < 4; ++r) inv[r] = (lrow[r] > 0.f) ? 1.f / lrow[r] : 0.f;
#pragma unroll
    for (int r = 0; r < 4; ++r) {
        const int qg = q0 + lhi * 4 + r;
        float* Yp = Y + ((size_t)b * SEQ + qg) * D_MODEL + h * HEAD_DIM;
#pragma unroll
        for (int d = 0; d < 4; ++d) Yp[l15 + 16 * d] = accO[d][r] * inv[r];
    }
}

// ---------------------------------------------------------------------------
extern "C" void kernel_launch(void* const* d_in, const int* in_sizes, int n_in,
                              void* d_out, int out_size, void* d_ws, size_t ws_size,
                              hipStream_t stream) {
    const float* x    = (const float*)d_in[0];
    const int*   mask = (const int*)  d_in[1];
    const float* Wq   = (const float*)d_in[2];
    const float* bq   = (const float*)d_in[3];
    const float* Wk   = (const float*)d_in[4];
    const float* bk   = (const float*)d_in[5];
    const float* Wv   = (const float*)d_in[6];
    const float* bv   = (const float*)d_in[7];
    const float* Wp   = (const float*)d_in[8];
    const float* bp   = (const float*)d_in[9];
    float* out = (float*)d_out;

    const size_t per = (size_t)BATCH * HEADS * SEQ * HEAD_DIM;  // 4M elements
    short* Q  = (short*)d_ws;
    short* Kb = Q + per;
    short* Vt = Kb + per;
    float* Y  = (float*)(Vt + per);  // [B,S,D] f32 (8B-aligned: per*2 bytes each, 8MB)

    const int M = BATCH * SEQ;
    dim3 blk(16, 16);
    dim3 grd(D_MODEL / 16, M / 16);

    gemm_bias<1><<<grd, blk, 0, stream>>>(x, Wq, bq, nullptr, Q,  M, D_MODEL, D_MODEL);
    gemm_bias<1><<<grd, blk, 0, stream>>>(x, Wk, bk, nullptr, Kb, M, D_MODEL, D_MODEL);
    gemm_bias<2><<<grd, blk, 0, stream>>>(x, Wv, bv, nullptr, Vt, M, D_MODEL, D_MODEL);

    flash_attn<<<dim3(BATCH * HEADS * (SEQ / QTILE)), 256, 0, stream>>>(Q, Kb, Vt, mask, Y);

    gemm_bias<0><<<grd, blk, 0, stream>>>(Y, Wp, bp, out, nullptr, M, D_MODEL, D_MODEL);
}

// Round 3
// 286.224 us; speedup vs baseline: 32.9885x; 7.6034x over previous
//
#include <hip/hip_runtime.h>
#include <math.h>

#define D_MODEL 1024
#define HEADS 16
#define HEAD_DIM 64
#define SEQ 2048
#define BATCH 2
#define KVT 64
#define QTILE 64

typedef __attribute__((ext_vector_type(8))) short bf16x8;
typedef __attribute__((ext_vector_type(4))) float f32x4;

__device__ __forceinline__ short f2bf(float f) {
    union { float f; unsigned u; } v; v.f = f;
    unsigned r = (v.u + 0x7FFFu + ((v.u >> 16) & 1u)) >> 16;
    return (short)r;
}

// ---------------------------------------------------------------------------
// f32 -> bf16 elementwise, 8 elems/thread
// ---------------------------------------------------------------------------
__global__ __launch_bounds__(256) void convert_bf16(
    const float* __restrict__ in, short* __restrict__ out, int n8) {
    int i = blockIdx.x * 256 + threadIdx.x;
    if (i >= n8) return;
    float4 a = ((const float4*)in)[2 * i];
    float4 b = ((const float4*)in)[2 * i + 1];
    short r[8] = {f2bf(a.x), f2bf(a.y), f2bf(a.z), f2bf(a.w),
                  f2bf(b.x), f2bf(b.y), f2bf(b.z), f2bf(b.w)};
    *(uint4*)(out + 8 * i) = *(uint4*)r;
}

// ---------------------------------------------------------------------------
// Transpose-convert weights: W [K=1024][N=1024] f32 -> Wt [N][K] bf16.
// z = 0,1,2 -> Wq,Wk,Wv into concatenated [3072][1024]; z=3 -> Wp.
// ---------------------------------------------------------------------------
__global__ __launch_bounds__(256) void wtrans(
    const float* __restrict__ Wq, const float* __restrict__ Wk,
    const float* __restrict__ Wv, const float* __restrict__ Wp,
    short* __restrict__ Wqkvt, short* __restrict__ Wpt) {
    __shared__ float t[32][33];
    const int z = blockIdx.z;
    const float* W = z == 0 ? Wq : z == 1 ? Wk : z == 2 ? Wv : Wp;
    short* dst = (z < 3) ? Wqkvt + (size_t)z * 1024 * 1024 : Wpt;
    const int n0 = blockIdx.x * 32, k0 = blockIdx.y * 32;
    const int tx = threadIdx.x & 31, ty = threadIdx.x >> 5;
#pragma unroll
    for (int j = 0; j < 4; ++j)
        t[ty + j * 8][tx] = W[(size_t)(k0 + ty + j * 8) * 1024 + n0 + tx];
    __syncthreads();
#pragma unroll
    for (int j = 0; j < 4; ++j) {
        const int n = ty + j * 8;
        dst[(size_t)(n0 + n) * 1024 + k0 + tx] = f2bf(t[tx][n]);
    }
}

// ---------------------------------------------------------------------------
// bf16 MFMA GEMM: C[M,N] = A[M,K] @ Bt[N,K]^T + bias
// 128x128 tile, BK=32, 4 waves (2x2 of 64x64), granule-swizzled LDS.
// MODE 0: f32 out row-major [M,N], bias b0.
// MODE 1: QKV fused (N=3072): bf16 head-split [B,H,S,Dh] into o0/o1/o2,
//         bias b0/b1/b2 per 1024-column third.
// ---------------------------------------------------------------------------
template <int MODE>
__global__ __launch_bounds__(256) void mfma_gemm(
    const short* __restrict__ A, const short* __restrict__ Bt,
    const float* __restrict__ b0, const float* __restrict__ b1,
    const float* __restrict__ b2, float* __restrict__ outf,
    short* __restrict__ o0, short* __restrict__ o1, short* __restrict__ o2,
    int M, int N, int K) {
    __shared__ short As[128 * 32];  // [row][granule] bf16, source pre-swizzled
    __shared__ short Bs[128 * 32];

    const int tid = threadIdx.x;
    const int wave = tid >> 6, lane = tid & 63;
    const int l15 = lane & 15, lhi = lane >> 4;
    const int wm = wave >> 1, wn = wave & 1;
    const int bm0 = blockIdx.y * 128, bn0 = blockIdx.x * 128;

    f32x4 acc[4][4];
#pragma unroll
    for (int m = 0; m < 4; ++m)
#pragma unroll
        for (int n = 0; n < 4; ++n) acc[m][n] = (f32x4){0.f, 0.f, 0.f, 0.f};

    // staging: o in [0,512): row r=o>>2, dest granule g=o&3,
    // source granule gs = g ^ ((r>>1)&3)  (undone at fragment read)
    uint4 av[2], bv[2];
#define LOADT(kt)                                                              \
    {                                                                          \
        const int k0 = (kt) * 32;                                              \
        _Pragma("unroll") for (int p = 0; p < 2; ++p) {                        \
            const int o = p * 256 + tid;                                       \
            const int r = o >> 2, g = o & 3;                                   \
            const int gs = g ^ ((r >> 1) & 3);                                 \
            av[p] = *(const uint4*)(A + (size_t)(bm0 + r) * K + k0 + gs * 8);  \
            bv[p] = *(const uint4*)(Bt + (size_t)(bn0 + r) * K + k0 + gs * 8); \
        }                                                                      \
    }

    LOADT(0);
    const int NT = K / 32;
    for (int kt = 0; kt < NT; ++kt) {
        __syncthreads();
#pragma unroll
        for (int p = 0; p < 2; ++p) {
            const int o = p * 256 + tid;
            *(uint4*)((char*)As + o * 16) = av[p];
            *(uint4*)((char*)Bs + o * 16) = bv[p];
        }
        __syncthreads();
        if (kt + 1 < NT) LOADT(kt + 1);
        bf16x8 af[4], bf[4];
        const int sg = (lhi ^ ((l15 >> 1) & 3)) * 16;
#pragma unroll
        for (int m = 0; m < 4; ++m)
            af[m] = *(const bf16x8*)((char*)As + (wm * 64 + m * 16 + l15) * 64 + sg);
#pragma unroll
        for (int n = 0; n < 4; ++n)
            bf[n] = *(const bf16x8*)((char*)Bs + (wn * 64 + n * 16 + l15) * 64 + sg);
#pragma unroll
        for (int m = 0; m < 4; ++m)
#pragma unroll
            for (int n = 0; n < 4; ++n)
                acc[m][n] = __builtin_amdgcn_mfma_f32_16x16x32_bf16(af[m], bf[n], acc[m][n], 0, 0, 0);
    }
#undef LOADT

    // epilogue: C[row][col], row=(lane>>4)*4+rr, col=lane&15 within fragment
#pragma unroll
    for (int m = 0; m < 4; ++m) {
#pragma unroll
        for (int n = 0; n < 4; ++n) {
            const int col = bn0 + wn * 64 + n * 16 + l15;
#pragma unroll
            for (int rr = 0; rr < 4; ++rr) {
                const int row = bm0 + wm * 64 + m * 16 + lhi * 4 + rr;
                const float v = acc[m][n][rr];
                if (MODE == 0) {
                    outf[(size_t)row * N + col] = v + b0[col];
                } else {
                    const int which = col >> 10;
                    const int cc = col & 1023;
                    const int h = cc >> 6, dh = cc & 63;
                    const int b = row >> 11, s = row & (SEQ - 1);
                    const float bias = (which == 0 ? b0 : which == 1 ? b1 : b2)[cc];
                    short* dst = which == 0 ? o0 : which == 1 ? o1 : o2;
                    dst[(((size_t)(b * HEADS + h)) * SEQ + s) * HEAD_DIM + dh] = f2bf(v + bias);
                }
            }
        }
    }
}

// ---------------------------------------------------------------------------
// V [B,H,S,Dh] bf16 -> Vt [B,H,Dh,S] bf16  (64x64 LDS tiles)
// ---------------------------------------------------------------------------
__global__ __launch_bounds__(256) void transpose_v(
    const short* __restrict__ V, short* __restrict__ Vt) {
    __shared__ short t[64][66];
    const int bh = blockIdx.y, s0 = blockIdx.x * 64;
    const int tx = threadIdx.x, ty = threadIdx.y;
    const short* src = V + ((size_t)bh * SEQ + s0) * 64;
#pragma unroll
    for (int j = 0; j < 16; ++j) {
        const int sl = ty * 16 + j;
        t[sl][tx] = src[(size_t)sl * 64 + tx];
    }
    __syncthreads();
    short* dst = Vt + (size_t)bh * 64 * SEQ + s0;
#pragma unroll
    for (int j = 0; j < 16; ++j) {
        const int dh = ty * 16 + j;
        dst[(size_t)dh * SEQ + tx] = t[tx][dh];
    }
}

// ---------------------------------------------------------------------------
// Flash attention, bf16 MFMA (unchanged from round 2 except bf16 Y output).
// ---------------------------------------------------------------------------
__global__ __launch_bounds__(256) void flash_attn(
    const short* __restrict__ Q, const short* __restrict__ K,
    const short* __restrict__ Vt, const int* __restrict__ mask,
    short* __restrict__ Y) {
    __shared__ unsigned char kt[KVT * 128];
    __shared__ unsigned char vt[HEAD_DIM * 128];
    __shared__ unsigned char pb[4][16 * 128];
    __shared__ float maskadd[KVT];

    const int tid = threadIdx.x;
    const int wave = tid >> 6;
    const int lane = tid & 63;
    const int l15 = lane & 15;
    const int lhi = lane >> 4;

    const int blk = blockIdx.x;
    const int qt = blk & 31;
    const int bh = blk >> 5;
    const int b = bh >> 4;
    const int h = bh & 15;

    const int q0 = qt * QTILE + wave * 16;

    const short* Qp = Q + ((size_t)bh * SEQ + q0 + l15) * HEAD_DIM;
    bf16x8 qf[2];
    qf[0] = *(const bf16x8*)(Qp + 8 * lhi);
    qf[1] = *(const bf16x8*)(Qp + 8 * lhi + 32);

    const unsigned char* Kb = (const unsigned char*)(K + (size_t)bh * SEQ * HEAD_DIM);
    const unsigned char* Vb = (const unsigned char*)(Vt + (size_t)bh * HEAD_DIM * SEQ);
    const int* mb = mask + b * SEQ;

    f32x4 accO[4];
    float mrow[4], lrow[4];
#pragma unroll
    for (int i = 0; i < 4; ++i) {
        accO[i] = (f32x4){0.f, 0.f, 0.f, 0.f};
        mrow[i] = -INFINITY;
        lrow[i] = 0.f;
    }

    for (int kv = 0; kv < SEQ / KVT; ++kv) {
        __syncthreads();
#pragma unroll
        for (int p = 0; p < 2; ++p) {
            const int o = p * 256 + tid;
            const int key = o >> 3;
            const int inner = (o & 7) * 16;
            uint4 d = *(const uint4*)(Kb + (size_t)kv * KVT * 128 + key * 128 + inner);
            *(uint4*)(kt + key * 128 + (inner ^ ((key & 7) << 4))) = d;
        }
#pragma unroll
        for (int p = 0; p < 2; ++p) {
            const int o = p * 256 + tid;
            const int dh = o >> 3;
            const int inner = (o & 7) * 16;
            uint4 d = *(const uint4*)(Vb + (size_t)dh * (SEQ * 2) + kv * 128 + inner);
            *(uint4*)(vt + dh * 128 + (inner ^ ((dh & 7) << 4))) = d;
        }
        if (tid < KVT) maskadd[tid] = mb[kv * KVT + tid] ? 0.f : -INFINITY;
        __syncthreads();

        f32x4 accS[4];
#pragma unroll
        for (int nt = 0; nt < 4; ++nt) accS[nt] = (f32x4){0.f, 0.f, 0.f, 0.f};
#pragma unroll
        for (int c = 0; c < 2; ++c) {
#pragma unroll
            for (int nt = 0; nt < 4; ++nt) {
                const int key = l15 + 16 * nt;
                bf16x8 kf = *(const bf16x8*)(kt + key * 128 +
                                             ((16 * lhi + 64 * c) ^ ((key & 7) << 4)));
                accS[nt] = __builtin_amdgcn_mfma_f32_16x16x32_bf16(qf[c], kf, accS[nt], 0, 0, 0);
            }
        }

        float sv[4][4];
#pragma unroll
        for (int nt = 0; nt < 4; ++nt) {
            const float ma = maskadd[l15 + 16 * nt];
#pragma unroll
            for (int r = 0; r < 4; ++r) sv[nt][r] = accS[nt][r] * 0.125f + ma;
        }

#pragma unroll
        for (int r = 0; r < 4; ++r) {
            float tmax = fmaxf(fmaxf(sv[0][r], sv[1][r]), fmaxf(sv[2][r], sv[3][r]));
#pragma unroll
            for (int m = 1; m < 16; m <<= 1) tmax = fmaxf(tmax, __shfl_xor(tmax, m, 16));
            const float mn = fmaxf(mrow[r], tmax);
            const float alpha = (mn == -INFINITY) ? 1.f : __expf(mrow[r] - mn);
            float p[4];
            float rs = 0.f;
#pragma unroll
            for (int nt = 0; nt < 4; ++nt) {
                p[nt] = (mn == -INFINITY) ? 0.f : __expf(sv[nt][r] - mn);
                rs += p[nt];
            }
#pragma unroll
            for (int m = 1; m < 16; m <<= 1) rs += __shfl_xor(rs, m, 16);
            lrow[r] = lrow[r] * alpha + rs;
            mrow[r] = mn;
#pragma unroll
            for (int d = 0; d < 4; ++d) accO[d][r] *= alpha;
            const int qrow = lhi * 4 + r;
            unsigned char* pw = pb[wave] + qrow * 128;
            const int sw = (qrow & 7) << 4;
#pragma unroll
            for (int nt = 0; nt < 4; ++nt)
                *(short*)(pw + (((l15 + 16 * nt) * 2) ^ sw)) = f2bf(p[nt]);
        }

#pragma unroll
        for (int c = 0; c < 2; ++c) {
            bf16x8 pf = *(const bf16x8*)(pb[wave] + l15 * 128 +
                                         ((16 * lhi + 64 * c) ^ ((l15 & 7) << 4)));
#pragma unroll
            for (int d = 0; d < 4; ++d) {
                const int dh = l15 + 16 * d;
                bf16x8 vf = *(const bf16x8*)(vt + dh * 128 +
                                             ((16 * lhi + 64 * c) ^ ((dh & 7) << 4)));
                accO[d] = __builtin_amdgcn_mfma_f32_16x16x32_bf16(pf, vf, accO[d], 0, 0, 0);
            }
        }
    }

    float inv[4];
#pragma unroll
    for (int r = 0; r < 4; ++r) inv[r] = (lrow[r] > 0.f) ? 1.f / lrow[r] : 0.f;
#pragma unroll
    for (int r = 0; r < 4; ++r) {
        const int qg = q0 + lhi * 4 + r;
        short* Yp = Y + ((size_t)b * SEQ + qg) * D_MODEL + h * HEAD_DIM;
#pragma unroll
        for (int d = 0; d < 4; ++d) Yp[l15 + 16 * d] = f2bf(accO[d][r] * inv[r]);
    }
}

// ---------------------------------------------------------------------------
extern "C" void kernel_launch(void* const* d_in, const int* in_sizes, int n_in,
                              void* d_out, int out_size, void* d_ws, size_t ws_size,
                              hipStream_t stream) {
    const float* x    = (const float*)d_in[0];
    const int*   mask = (const int*)  d_in[1];
    const float* Wq   = (const float*)d_in[2];
    const float* bq   = (const float*)d_in[3];
    const float* Wk   = (const float*)d_in[4];
    const float* bk   = (const float*)d_in[5];
    const float* Wv   = (const float*)d_in[6];
    const float* bv   = (const float*)d_in[7];
    const float* Wp   = (const float*)d_in[8];
    const float* bp   = (const float*)d_in[9];
    float* out = (float*)d_out;

    short* ws    = (short*)d_ws;
    short* xb    = ws;                          // 4M
    short* Wqkvt = xb + ((size_t)4 << 20);      // 3M
    short* Wpt   = Wqkvt + ((size_t)3 << 20);   // 1M
    short* Qb    = Wpt + ((size_t)1 << 20);     // 4M
    short* Kb    = Qb + ((size_t)4 << 20);      // 4M
    short* Vb    = Kb + ((size_t)4 << 20);      // 4M
    short* Vtb   = Vb + ((size_t)4 << 20);      // 4M
    short* Yb    = Vtb + ((size_t)4 << 20);     // 4M

    const int M = BATCH * SEQ;  // 4096

    convert_bf16<<<dim3((M * D_MODEL / 8 + 255) / 256), 256, 0, stream>>>(x, xb, M * D_MODEL / 8);
    wtrans<<<dim3(32, 32, 4), 256, 0, stream>>>(Wq, Wk, Wv, Wp, Wqkvt, Wpt);

    mfma_gemm<1><<<dim3(3 * D_MODEL / 128, M / 128), 256, 0, stream>>>(
        xb, Wqkvt, bq, bk, bv, nullptr, Qb, Kb, Vb, M, 3 * D_MODEL, D_MODEL);

    transpose_v<<<dim3(SEQ / 64, BATCH * HEADS), dim3(64, 4), 0, stream>>>(Vb, Vtb);

    flash_attn<<<dim3(BATCH * HEADS * (SEQ / QTILE)), 256, 0, stream>>>(Qb, Kb, Vtb, mask, Yb);

    mfma_gemm<0><<<dim3(D_MODEL / 128, M / 128), 256, 0, stream>>>(
        Yb, Wpt, bp, bp, bp, out, nullptr, nullptr, nullptr, M, D_MODEL, D_MODEL);
}